// Round 5
// baseline (177.923 us; speedup 1.0000x reference)
//
#include <hip/hip_runtime.h>
#include <hip/hip_bf16.h>
#include <hip/hip_cooperative_groups.h>

namespace cg = cooperative_groups;

// Problem constants (from setup_inputs): price_data float32 [64, 4096, 64]
#define B 64
#define S 4096
#define C 64
#define NCHUNK 16            // s-chunks per batch; block = (b, chunk)
#define LCH (S / NCHUNK)     // 256 s per block
#define SPT (LCH / 16)       // 16 s per thread-slice (16 slices per block)

// native clang vector type (usable with __builtin_nontemporal_store)
typedef float f32x4 __attribute__((ext_vector_type(4)));

// Partials in ws: part[p][ (b*NCHUNK + chunk)*64 + c ], p: 0=sum 1=sumsq
// 2=gain 3=loss 4=sum12 5=sum26
#define PSTRIDE ((size_t)B * NCHUNK * 64)   // 65536 floats per plane

__device__ inline f32x4 vmax0(f32x4 a) {
    f32x4 r;
    r.x = fmaxf(a.x, 0.f);
    r.y = fmaxf(a.y, 0.f);
    r.z = fmaxf(a.z, 0.f);
    r.w = fmaxf(a.w, 0.f);
    return r;
}

__global__ __launch_bounds__(256) void ti_fused(const f32x4* __restrict__ in4,
                                                f32x4* __restrict__ out4,
                                                float* __restrict__ part) {
    const int blk  = blockIdx.x;        // 0..1023
    const int b    = blk >> 4;          // 0..63
    const int half = blk & 15;          // chunk 0..15
    const int tid  = threadIdx.x;
    const int w    = tid >> 6;          // wave 0..3
    const int lane = tid & 63;
    const int sl   = tid >> 4;          // s-slice 0..15
    const int c4   = tid & 15;          // float4 channel group 0..15

    __shared__ f32x4 red[4][6][16];     // 6 KB  — cross-wave reduce
    __shared__ float sums[6][64];       // 1.5 KB — per-b raw sums
    __shared__ f32x4 st4[4][16];        // 1 KB  — final stats table

    // ---------------- Phase A: reduce + copy channels [0,64) ----------------
    const size_t rowbase = (size_t)b * S;
    const int s0 = half * LCH + sl * SPT;

    f32x4 acc[6];
    #pragma unroll
    for (int p = 0; p < 6; ++p) acc[p] = (f32x4){0.f, 0.f, 0.f, 0.f};

    f32x4 prev = (f32x4){0.f, 0.f, 0.f, 0.f};
    if (s0 > 0) prev = in4[(rowbase + s0 - 1) * 16 + c4];

    #pragma unroll 4
    for (int j = 0; j < SPT; ++j) {
        const int s = s0 + j;
        const size_t r = rowbase + s;
        const f32x4 v = in4[r * 16 + c4];
        __builtin_nontemporal_store(v, &out4[r * 80 + c4]);   // copy region
        acc[0] += v;
        acc[1] += v * v;
        if (s > 0) {
            const f32x4 d = v - prev;
            acc[2] += vmax0(d);
            acc[3] += vmax0(-d);
        }
        prev = v;
        if (s >= S - 26) {
            acc[5] += v;
            if (s >= S - 12) acc[4] += v;
        }
    }

    // intra-wave reduce across the wave's 4 slices (lanes ±16, ±32)
    #pragma unroll
    for (int p = 0; p < 6; ++p) {
        #pragma unroll
        for (int k = 0; k < 4; ++k) {
            float t = acc[p][k];
            t += __shfl_xor(t, 16);
            t += __shfl_xor(t, 32);
            acc[p][k] = t;
        }
    }
    if (lane < 16) {
        #pragma unroll
        for (int p = 0; p < 6; ++p) red[w][p][c4] = acc[p];
    }
    __syncthreads();
    if (tid < 96) {
        const int p = tid >> 4, cc = tid & 15;
        f32x4 t = red[0][p][cc] + red[1][p][cc] + red[2][p][cc] + red[3][p][cc];
        *(f32x4*)&part[(size_t)p * PSTRIDE +
                       (size_t)(b * NCHUNK + half) * 64 + cc * 4] = t;
    }

    cg::this_grid().sync();   // device-scope fence + grid barrier

    // ------------- Phase B: per-block stats for this block's b -------------
    {
        // wave w sums plane w; waves 0,1 additionally sum planes 4,5
        const int c = lane;
        {
            float a = 0.f;
            #pragma unroll 4
            for (int ch = 0; ch < NCHUNK; ++ch)
                a += part[(size_t)w * PSTRIDE + (size_t)(b * NCHUNK + ch) * 64 + c];
            sums[w][c] = a;
        }
        if (w < 2) {
            const int p1 = 4 + w;
            float a = 0.f;
            #pragma unroll 4
            for (int ch = 0; ch < NCHUNK; ++ch)
                a += part[(size_t)p1 * PSTRIDE + (size_t)(b * NCHUNK + ch) * 64 + c];
            sums[p1][c] = a;
        }
        __syncthreads();

        if (tid < 64) {
            const float sum = sums[0][tid], sumsq = sums[1][tid];
            const float gain = sums[2][tid], loss = sums[3][tid];
            const float s12 = sums[4][tid], s26 = sums[5][tid];

            const float inv_sm1 = 1.f / (float)(S - 1);
            const float ag = gain * inv_sm1;
            const float al = loss * inv_sm1;
            const float rs = ag / (al + 1e-7f);
            const float rsi = 100.f - 100.f / (1.f + rs);

            const float macd = s12 * (1.f / 12.f) - s26 * (1.f / 26.f);

            const float sma = sum * (1.f / (float)S);
            const float var = sumsq * (1.f / (float)S) - sma * sma;
            const float sd = sqrtf(fmaxf(var, 0.f));

            float* stf = (float*)st4;   // stf[which*64 + c]
            stf[0 * 64 + tid] = rsi;
            stf[1 * 64 + tid] = macd;
            stf[2 * 64 + tid] = sma + 2.f * sd;
            stf[3 * 64 + tid] = sma - 2.f * sd;
        }
        __syncthreads();
    }

    // ---------- Phase C: broadcast channels [64,320) for 256 rows ----------
    {
        const int q = lane;                 // 0..63, loop-invariant
        const int which = q >> 4;
        const int cc = q & 15;
        const f32x4 v = st4[which][cc];

        const size_t base_row = rowbase + (size_t)half * LCH;
        #pragma unroll 8
        for (int pass = 0; pass < 64; ++pass) {
            const size_t row = base_row + pass * 4 + w;
            __builtin_nontemporal_store(v, &out4[row * 80 + 16 + q]);
        }
    }
}

extern "C" void kernel_launch(void* const* d_in, const int* in_sizes, int n_in,
                              void* d_out, int out_size, void* d_ws, size_t ws_size,
                              hipStream_t stream) {
    const f32x4* in4 = (const f32x4*)d_in[0];
    f32x4* out4 = (f32x4*)d_out;
    float* part = (float*)d_ws;            // 6 * 65536 floats = 1.5 MB

    void* args[] = { (void*)&in4, (void*)&out4, (void*)&part };
    hipLaunchCooperativeKernel((const void*)ti_fused, dim3(64 * NCHUNK), dim3(256),
                               args, 0, stream);
}

// Round 6
// 78.999 us; speedup vs baseline: 2.2522x; 2.2522x over previous
//
#include <hip/hip_runtime.h>
#include <hip/hip_bf16.h>

// Problem constants (from setup_inputs): price_data float32 [64, 4096, 64]
#define B 64
#define S 4096
#define C 64
#define NCHUNK 8             // s-chunks per batch in K1; block = (b, chunk)
#define LCH (S / NCHUNK)     // 512 s per K1 block
#define SPT (LCH / 16)       // 32 s per thread-slice (16 slices per block)

// native clang vector type (usable with __builtin_nontemporal_store)
typedef float f32x4 __attribute__((ext_vector_type(4)));

// Partials in ws: part[p][ (b*NCHUNK + chunk)*64 + c ], p: 0=sum 1=sumsq
// 2=gain 3=loss 4=sum12 5=sum26
#define PSTRIDE ((size_t)B * NCHUNK * 64)   // 32768 floats per plane (768 KB total)

__device__ inline f32x4 vmax0(f32x4 a) {
    f32x4 r;
    r.x = fmaxf(a.x, 0.f);
    r.y = fmaxf(a.y, 0.f);
    r.z = fmaxf(a.z, 0.f);
    r.w = fmaxf(a.w, 0.f);
    return r;
}

// K1: fused input-copy (out channels [0,64)) + partial reductions.
// 512 blocks x 256 threads. tid = slice*16 + c4; 16B/lane loads & stores.
__global__ __launch_bounds__(256) void ti_copy_reduce(const f32x4* __restrict__ in4,
                                                      f32x4* __restrict__ out4,
                                                      float* __restrict__ part) {
    const int b     = blockIdx.x / NCHUNK;
    const int chunk = blockIdx.x % NCHUNK;
    const int tid   = threadIdx.x;
    const int sl    = tid >> 4;     // s-slice 0..15
    const int c4    = tid & 15;     // float4 channel group 0..15
    const int s0    = chunk * LCH + sl * SPT;

    const size_t rowbase = (size_t)b * S;

    f32x4 acc[6];
    #pragma unroll
    for (int p = 0; p < 6; ++p) acc[p] = (f32x4){0.f, 0.f, 0.f, 0.f};

    f32x4 prev = (f32x4){0.f, 0.f, 0.f, 0.f};
    if (s0 > 0) prev = in4[(rowbase + s0 - 1) * 16 + c4];

    #pragma unroll 8
    for (int j = 0; j < SPT; ++j) {
        const int s = s0 + j;
        const size_t r = rowbase + s;
        const f32x4 v = in4[r * 16 + c4];
        __builtin_nontemporal_store(v, &out4[r * 80 + c4]);   // copy region
        acc[0] += v;
        acc[1] += v * v;
        if (s > 0) {
            const f32x4 d = v - prev;
            acc[2] += vmax0(d);
            acc[3] += vmax0(-d);
        }
        prev = v;
        if (s >= S - 26) {
            acc[5] += v;
            if (s >= S - 12) acc[4] += v;
        }
    }

    // Cross-slice reduce in LDS: lds[p][sl][ch]
    __shared__ float lds[6][16][64];
    #pragma unroll
    for (int p = 0; p < 6; ++p) *(f32x4*)&lds[p][sl][c4 * 4] = acc[p];
    __syncthreads();

    if (tid < 64) {
        const size_t idx = ((size_t)(b * NCHUNK + chunk)) * 64 + tid;
        #pragma unroll
        for (int p = 0; p < 6; ++p) {
            float t = 0.f;
            #pragma unroll
            for (int s2 = 0; s2 < 16; ++s2) t += lds[p][s2][tid];
            part[(size_t)p * PSTRIDE + idx] = t;
        }
    }
}

// K2: fold partials -> stats (redundantly per block, cheap) + broadcast
// channels [64,320). 2048 blocks x 256 threads; block = (b, 128-row segment).
__global__ __launch_bounds__(256) void ti_stats_broadcast(const float* __restrict__ part,
                                                          f32x4* __restrict__ out4) {
    const int blk  = blockIdx.x;
    const int b    = blk >> 5;          // 0..63
    const int seg  = blk & 31;          // 0..31 (128 rows each)
    const int tid  = threadIdx.x;
    const int w    = tid >> 6;          // wave 0..3
    const int lane = tid & 63;

    __shared__ float sums[6][64];
    __shared__ f32x4 st4[4][16];

    // ---- fold partials for this b: plane w (+ planes 4,5 on waves 0,1) ----
    {
        float a = 0.f;
        #pragma unroll
        for (int ch = 0; ch < NCHUNK; ++ch)
            a += part[(size_t)w * PSTRIDE + (size_t)(b * NCHUNK + ch) * 64 + lane];
        sums[w][lane] = a;
        if (w < 2) {
            const int p1 = 4 + w;
            float a2 = 0.f;
            #pragma unroll
            for (int ch = 0; ch < NCHUNK; ++ch)
                a2 += part[(size_t)p1 * PSTRIDE + (size_t)(b * NCHUNK + ch) * 64 + lane];
            sums[p1][lane] = a2;
        }
    }
    __syncthreads();

    if (tid < 64) {
        const float sum = sums[0][tid], sumsq = sums[1][tid];
        const float gain = sums[2][tid], loss = sums[3][tid];
        const float s12 = sums[4][tid], s26 = sums[5][tid];

        const float inv_sm1 = 1.f / (float)(S - 1);
        const float ag = gain * inv_sm1;
        const float al = loss * inv_sm1;
        const float rs = ag / (al + 1e-7f);
        const float rsi = 100.f - 100.f / (1.f + rs);

        const float macd = s12 * (1.f / 12.f) - s26 * (1.f / 26.f);

        const float sma = sum * (1.f / (float)S);
        const float var = sumsq * (1.f / (float)S) - sma * sma;
        const float sd = sqrtf(fmaxf(var, 0.f));

        float* stf = (float*)st4;   // stf[which*64 + c]
        stf[0 * 64 + tid] = rsi;
        stf[1 * 64 + tid] = macd;
        stf[2 * 64 + tid] = sma + 2.f * sd;
        stf[3 * 64 + tid] = sma - 2.f * sd;
    }
    __syncthreads();

    // ---- broadcast channels [64,320) for 128 rows ----
    const int q = lane;                 // 0..63, loop-invariant
    const f32x4 v = st4[q >> 4][q & 15];

    const size_t base_row = (size_t)b * S + (size_t)seg * 128;
    #pragma unroll 8
    for (int pass = 0; pass < 32; ++pass) {
        const size_t row = base_row + pass * 4 + w;   // 1KB contiguous per wave
        __builtin_nontemporal_store(v, &out4[row * 80 + 16 + q]);
    }
}

extern "C" void kernel_launch(void* const* d_in, const int* in_sizes, int n_in,
                              void* d_out, int out_size, void* d_ws, size_t ws_size,
                              hipStream_t stream) {
    const f32x4* in4 = (const f32x4*)d_in[0];
    f32x4* out4 = (f32x4*)d_out;
    float* part = (float*)d_ws;            // 6 * 32768 floats = 768 KB

    ti_copy_reduce<<<B * NCHUNK, 256, 0, stream>>>(in4, out4, part);
    ti_stats_broadcast<<<B * 32, 256, 0, stream>>>(part, out4);
}